// Round 24
// baseline (126.820 us; speedup 1.0000x reference)
//
#include <hip/hip_runtime.h>
#include <cstdint>
#include <cstddef>

#define NIMG 32
#define NCLS 81
#define NC1  80
#define NBOX 8732
#define CAP  65536
#define TOPK 400
#define MAXOUT 100
#define KW   7             // 400 bits -> 7 u64 words
#define COLCAP 2048
#define BDEC 128
#define CNTSTRIDE 16       // one counter per 64B line
#define RSTRIDE 409        // LDS row stride (u64), odd -> conflict-free w-column reads

constexpr size_t TOTAL_S = (size_t)NIMG * NCLS * NBOX;

__device__ __forceinline__ unsigned int f2sort(float f) {
    unsigned int u = __float_as_uint(f);
    return (u & 0x80000000u) ? ~u : (u | 0x80000000u);
}

// ============ kernel 0: zero the per-image counters ============
__global__ __launch_bounds__(512) void k_zero(int* __restrict__ cnt) {
    cnt[threadIdx.x] = 0;    // NIMG * CNTSTRIDE = 512 ints
}

// ============ kernel 1: decode + coalesced-staged LDS softmax + mask filter ============
// Stage tile[81][128] once with float4 cooperative loads (1 KB/wave granule),
// then each thread processes its own column from LDS. Exact reference arithmetic.
__global__ __launch_bounds__(BDEC) void k_decode(const float* __restrict__ bboxes,
        const float* __restrict__ scores, const float* __restrict__ dbox,
        float4* __restrict__ oboxes, uint2* __restrict__ cand, int* __restrict__ cnt) {
    __shared__ float tile[NCLS * BDEC];   // 41.5 KB
    int n = blockIdx.y;
    int tid = threadIdx.x;
    int lane = tid & 63;
    int b0 = blockIdx.x * BDEC;
    int b = b0 + tid;
    bool live = (b < NBOX);

    // ---- cooperative coalesced staging: 81 rows x 32 float4 ----
    const size_t sbase = (size_t)n * NCLS * NBOX + b0;
    const int NQ = NCLS * (BDEC / 4);     // 2592
    for (int idx = tid; idx < NQ; idx += BDEC) {
        int c = idx >> 5;                 // class row (32 float4 per row)
        int q = idx & 31;
        size_t g = sbase + (size_t)c * NBOX + 4 * q;
        float4 v;
        if (g + 3 < TOTAL_S) {
            v = *reinterpret_cast<const float4*>(scores + g);
        } else {
            v.x = (g     < TOTAL_S) ? scores[g]     : 0.f;
            v.y = (g + 1 < TOTAL_S) ? scores[g + 1] : 0.f;
            v.z = (g + 2 < TOTAL_S) ? scores[g + 2] : 0.f;
            v.w = 0.f;
        }
        *reinterpret_cast<float4*>(&tile[c * BDEC + 4 * q]) = v;
    }

    // ---- box decode (independent loads, overlaps staging) ----
    bool go = false;
    float l = 0.f, tt = 0.f, r = 0.f, bo = 0.f;
    if (live) {
        const float* bp = bboxes + (size_t)n * 4 * NBOX + b;
        float bx = bp[0], by = bp[NBOX], bw = bp[2 * NBOX], bh = bp[3 * NBOX];
        float4 d = reinterpret_cast<const float4*>(dbox)[b];
        float cx = 0.1f * bx * d.z + d.x;
        float cy = 0.1f * by * d.w + d.y;
        float ww = expf(0.2f * bw) * d.z;
        float hh = expf(0.2f * bh) * d.w;
        l = cx - 0.5f * ww;  tt = cy - 0.5f * hh;
        r = cx + 0.5f * ww;  bo = cy + 0.5f * hh;
        l = fminf(fmaxf(l, 0.f), 1.f);  tt = fminf(fmaxf(tt, 0.f), 1.f);
        r = fminf(fmaxf(r, 0.f), 1.f);  bo = fminf(fmaxf(bo, 0.f), 1.f);
        const float MINS = 1.0f / 300.0f;
        go = (r - l >= MINS) && (bo - tt >= MINS);
    }
    __syncthreads();

    // ---- max over classes (sequential chain, reference order 0..80) ----
    float m = -3.4e38f;
    #pragma unroll
    for (int c = 0; c < NCLS; ++c) m = fmaxf(m, tile[c * BDEC + tid]);

    // ---- exp in place (own column, no race) + exact serial-order sum ----
    float ss = 0.f;
    #pragma unroll
    for (int c = 0; c < NCLS; ++c) {
        float e = expf(tile[c * BDEC + tid] - m);
        tile[c * BDEC + tid] = e;
        ss += e;
    }

    // ---- mul-compare filter with exact gray-zone fallback (== e/ss > 0.05f exactly) ----
    float t05 = 0.05f * ss;
    float thi = t05 * 1.000001f;
    float tlo = t05 * 0.999999f;
    unsigned long long mlo = 0ull;   // classes 1..64
    unsigned int       mhi = 0u;     // classes 65..80
    #pragma unroll
    for (int c = 1; c < NCLS; ++c) {
        float e = tile[c * BDEC + tid];
        bool bit;
        if (e > thi)       bit = true;
        else if (e < tlo)  bit = false;
        else               bit = (e / ss > 0.05f);   // rare exact resolve
        if (go && bit) {
            if (c <= 64) mlo |= 1ull << (c - 1);
            else         mhi |= 1u << (c - 65);
        }
    }

    // ---- wave-aggregated reservation ----
    int nc = (int)__popcll(mlo) + __popc(mhi);
    int incl = nc;
    #pragma unroll
    for (int off = 1; off < 64; off <<= 1) {
        int u = __shfl_up(incl, off);
        if (lane >= off) incl += u;
    }
    int excl = incl - nc;
    int tot = __shfl(incl, 63);
    int base = 0;
    if (lane == 0 && tot > 0) base = atomicAdd(&cnt[n * CNTSTRIDE], tot);
    base = __shfl(base, 0);

    // ---- sparse emit: e from LDS (runtime c ok), exact IEEE divide ----
    if (nc > 0) {
        int pos = base + excl;
        uint2* cp = cand + (size_t)n * CAP;
        unsigned long long ml = mlo;
        while (ml) {
            int bit = (int)__ffsll((long long)ml) - 1; ml &= ml - 1;
            int c = bit + 1;
            float p = tile[c * BDEC + tid] / ss;
            if (pos < CAP) cp[pos] = make_uint2(__float_as_uint(p),
                                                (unsigned)(b * NC1 + (c - 1)));
            ++pos;
        }
        unsigned int mh = mhi;
        while (mh) {
            int bit = __ffs(mh) - 1; mh &= mh - 1;
            int c = bit + 65;
            float p = tile[c * BDEC + tid] / ss;
            if (pos < CAP) cp[pos] = make_uint2(__float_as_uint(p),
                                                (unsigned)(b * NC1 + (c - 1)));
            ++pos;
        }
        oboxes[(size_t)n * NBOX + b] = make_float4(l, tt, r, bo);
    }
}

// ============ LDS bitonic sort (descending), u64 keys, n = pow2 ============
__device__ void bitonic_desc(unsigned long long* arr, int nn, int tid, int nt) {
    for (int k = 2; k <= nn; k <<= 1) {
        for (int j = k >> 1; j > 0; j >>= 1) {
            __syncthreads();
            for (int i = tid; i < nn; i += nt) {
                int ixj = i ^ j;
                if (ixj > i) {
                    unsigned long long a = arr[i], b = arr[ixj];
                    bool desc = ((i & k) == 0);
                    bool sw = desc ? (a < b) : (a > b);
                    if (sw) { arr[i] = b; arr[ixj] = a; }
                }
            }
        }
    }
    __syncthreads();
}

// ============ kernel 2: per-image top-400 selection, write records (R20 verbatim) ============
__global__ __launch_bounds__(1024) void k_topk(const float4* __restrict__ boxes,
        const uint2* __restrict__ cand, const int* __restrict__ cnt,
        float* __restrict__ g_sc, float4* __restrict__ g_cb, int* __restrict__ g_lab,
        float4* __restrict__ g_ob, float* __restrict__ g_ar, int* __restrict__ g_nsel) {
    __shared__ int hist[1024];
    __shared__ unsigned long long keys[COLCAP];
    __shared__ int s_T, s_pos;

    int n = blockIdx.x;
    int tid = threadIdx.x;
    int lane = tid & 63;
    unsigned long long lmlt = (1ull << lane) - 1ull;
    int M = cnt[n * CNTSTRIDE]; if (M > CAP) M = CAP;
    const uint2* cp = cand + (size_t)n * CAP;

    hist[tid] = 0;
    if (tid == 0) s_pos = 0;
    __syncthreads();

    for (int i = tid; i < M; i += 1024) {
        unsigned int bits = cp[i].x;
        int bk = (int)(bits >> 16) - 0x3D00;
        bk = max(0, min(1023, bk));
        atomicAdd(&hist[bk], 1);
    }
    __syncthreads();

    if (tid < 64) {
        int sl = 0;
        #pragma unroll
        for (int t = 0; t < 16; ++t) sl += hist[tid * 16 + t];
        int incl = sl;
        #pragma unroll
        for (int off = 1; off < 64; off <<= 1) {
            int v = __shfl_down(incl, off);
            if (tid + off < 64) incl += v;
        }
        int xl = incl - sl;
        int tc = -1, cum = xl;
        for (int t = 15; t >= 0; --t) {
            cum += hist[tid * 16 + t];
            if (cum >= TOPK) { tc = tid * 16 + t; break; }
        }
        #pragma unroll
        for (int off = 32; off > 0; off >>= 1)
            tc = max(tc, __shfl_xor(tc, off));
        if (tid == 0) s_T = max(tc, 0);
    }
    __syncthreads();
    int T = s_T;

    int iters = (M + 1023) / 1024;
    for (int it = 0; it < iters; ++it) {
        int i = it * 1024 + tid;
        bool pred = false; unsigned long long key = 0ull;
        if (i < M) {
            uint2 e = cp[i];
            int bk = (int)(e.x >> 16) - 0x3D00;
            bk = max(0, min(1023, bk));
            if (bk >= T) {
                pred = true;
                key = ((unsigned long long)e.x << 32) | (unsigned int)(~e.y);
            }
        }
        unsigned long long mask = __ballot(pred);
        int base = 0;
        if (lane == 0) {
            int cw = (int)__popcll(mask);
            if (cw) base = atomicAdd(&s_pos, cw);
        }
        base = __shfl(base, 0);
        if (pred) {
            int pos = base + (int)__popcll(mask & lmlt);
            if (pos < COLCAP) keys[pos] = key;
        }
    }
    __syncthreads();
    int ncol = min(s_pos, COLCAP);

    int nsort = 512;
    while (nsort < ncol) nsort <<= 1;
    for (int i = ncol + tid; i < nsort; i += 1024) keys[i] = 0ull;
    __syncthreads();
    bitonic_desc(keys, nsort, tid, 1024);

    int nsel = min(TOPK, ncol);
    if (tid < TOPK) {
        int i = tid;
        float sc = -1.0f; float4 cb = make_float4(0.f, 0.f, 0.f, 0.f);
        int lab = 0; float4 ob = cb; float ar = 0.f;
        if (i < nsel) {
            unsigned long long key = keys[i];
            unsigned int bits = (unsigned int)(key >> 32);
            unsigned int flat = ~(unsigned int)key;
            int bb = (int)(flat / NC1);
            lab = (int)(flat - (unsigned)bb * NC1) + 1;
            sc = __uint_as_float(bits);
            cb = boxes[(size_t)n * NBOX + bb];
            float off = 2.0f * (float)lab;
            ob = make_float4(cb.x + off, cb.y + off, cb.z + off, cb.w + off);
            ar = fmaxf(ob.z - ob.x, 0.f) * fmaxf(ob.w - ob.y, 0.f);
        }
        size_t gi = (size_t)n * TOPK + i;
        g_sc[gi] = sc; g_cb[gi] = cb; g_lab[gi] = lab; g_ob[gi] = ob; g_ar[gi] = ar;
    }
    if (tid == 0) g_nsel[n] = nsel;
}

// ============ kernel 3: IoU suppression-mask words, grid (KW, NIMG) ============
__global__ __launch_bounds__(256) void k_iou(const float4* __restrict__ g_ob,
        const float* __restrict__ g_ar, const int* __restrict__ g_nsel,
        unsigned long long* __restrict__ g_rows) {
    __shared__ float4 s_ob[TOPK];
    __shared__ float  s_ar[TOPK];
    int n = blockIdx.y, w = blockIdx.x;
    int tid = threadIdx.x;
    for (int i = tid; i < TOPK; i += 256) {
        s_ob[i] = g_ob[(size_t)n * TOPK + i];
        s_ar[i] = g_ar[(size_t)n * TOPK + i];
    }
    __syncthreads();
    int nsel = g_nsel[n];
    int j0 = w * 64;
    unsigned long long* gr = g_rows + ((size_t)n * KW + w) * TOPK;
    for (int i = tid; i < TOPK; i += 256) {
        unsigned long long cur = 0ull;
        if (i < nsel) {
            float4 oi = s_ob[i]; float ai = s_ar[i];
            int jend = min(j0 + 64, nsel);
            for (int j = j0; j < jend; ++j) {
                if (j > i) {
                    float4 oj = s_ob[j];
                    float lx = fmaxf(oi.x, oj.x), ly = fmaxf(oi.y, oj.y);
                    float rx = fminf(oi.z, oj.z), ry = fminf(oi.w, oj.w);
                    float inter = fmaxf(rx - lx, 0.f) * fmaxf(ry - ly, 0.f);
                    float uni = fmaxf(ai + s_ar[j] - inter, 1e-12f);
                    cur |= ((unsigned long long)(inter / uni > 0.5f)) << (j - j0);
                }
            }
        }
        gr[i] = cur;   // coalesced in i
    }
}

// ============ kernel 4: nz-skipping serial NMS + rank-compact output ============
__global__ __launch_bounds__(512) void k_nms(const unsigned long long* __restrict__ g_rows,
        const float* __restrict__ g_sc, const float4* __restrict__ g_cb,
        const int* __restrict__ g_lab, const int* __restrict__ g_nsel,
        float* __restrict__ out) {
    __shared__ unsigned long long rows[KW * RSTRIDE];   // [w][i], stride 409
    __shared__ unsigned long long nz[8];
    __shared__ unsigned long long s_keep[KW];
    __shared__ int pc[KW + 1];

    int n = blockIdx.x;
    int tid = threadIdx.x;
    int lane = tid & 63;
    int nsel = g_nsel[n];

    const unsigned long long* gr = g_rows + (size_t)n * KW * TOPK;
    for (int t = tid; t < KW * TOPK; t += 512) {
        int w = t / TOPK, i = t - w * TOPK;
        rows[w * RSTRIDE + i] = gr[t];
    }
    __syncthreads();

    {
        unsigned long long v = 0ull;
        if (tid < TOPK) {
            #pragma unroll
            for (int w = 0; w < KW; ++w) v |= rows[w * RSTRIDE + tid];
        }
        unsigned long long bal = __ballot(v != 0ull);
        if (lane == 0) nz[tid >> 6] = bal;
    }
    __syncthreads();

    if (tid < 64) {
        unsigned long long keepw = 0ull;
        if (lane < KW) {
            int lo = lane << 6;
            keepw = (nsel >= lo + 64) ? ~0ull
                  : (nsel <= lo ? 0ull : ((1ull << (nsel - lo)) - 1ull));
        }
        #pragma unroll
        for (int w = 0; w < KW; ++w) {
            unsigned long long nzw = nz[w];
            while (nzw) {
                int bq = (int)__ffsll((long long)nzw) - 1;
                nzw &= nzw - 1;
                int i = (w << 6) + bq;
                unsigned long long row = (lane < KW) ? rows[lane * RSTRIDE + i] : 0ull;
                unsigned long long kwv = __shfl(keepw, w);
                if ((kwv >> bq) & 1ull) keepw &= ~row;
            }
        }
        if (lane < KW) s_keep[lane] = keepw;
    }
    __syncthreads();

    if (tid == 0) {
        int acc = 0;
        #pragma unroll
        for (int w = 0; w < KW; ++w) { pc[w] = acc; acc += (int)__popcll(s_keep[w]); }
        pc[KW] = acc;
    }
    __syncthreads();

    float* obox = out;
    float* olab = out + (size_t)NIMG * MAXOUT * 4;
    float* osco = out + (size_t)NIMG * MAXOUT * 5;
    int nkept = pc[KW];

    if (tid < TOPK) {
        unsigned long long kw = s_keep[tid >> 6];
        bool kb = (kw >> (tid & 63)) & 1ull;
        if (kb) {
            int rank = pc[tid >> 6] + (int)__popcll(kw & ((1ull << (tid & 63)) - 1ull));
            if (rank < MAXOUT) {
                size_t gi = (size_t)n * TOPK + tid;
                float4 cb = g_cb[gi];
                size_t bo_ = ((size_t)n * MAXOUT + rank) * 4;
                obox[bo_ + 0] = cb.x; obox[bo_ + 1] = cb.y;
                obox[bo_ + 2] = cb.z; obox[bo_ + 3] = cb.w;
                olab[(size_t)n * MAXOUT + rank] = (float)g_lab[gi];
                osco[(size_t)n * MAXOUT + rank] = g_sc[gi];
            }
        }
    }
    if (tid < MAXOUT && tid >= nkept) {
        size_t bo_ = ((size_t)n * MAXOUT + tid) * 4;
        obox[bo_ + 0] = 0.f; obox[bo_ + 1] = 0.f; obox[bo_ + 2] = 0.f; obox[bo_ + 3] = 0.f;
        olab[(size_t)n * MAXOUT + tid] = 0.f;
        osco[(size_t)n * MAXOUT + tid] = 0.f;
    }
}

extern "C" void kernel_launch(void* const* d_in, const int* in_sizes, int n_in,
                              void* d_out, int out_size, void* d_ws, size_t ws_size,
                              hipStream_t stream) {
    (void)in_sizes; (void)n_in; (void)out_size; (void)ws_size;
    const float* bboxes = (const float*)d_in[0];
    const float* scores = (const float*)d_in[1];
    const float* dbox   = (const float*)d_in[2];
    float* out = (float*)d_out;

    char* ws = (char*)d_ws;
    size_t off = 0;
    float4* oboxes = (float4*)(ws + off); off += (size_t)NIMG * NBOX * sizeof(float4);
    int* cnt = (int*)(ws + off); off += (size_t)NIMG * CNTSTRIDE * sizeof(int);
    uint2* cand = (uint2*)(ws + off); off += (size_t)NIMG * CAP * sizeof(uint2);
    float* g_sc = (float*)(ws + off); off += (size_t)NIMG * TOPK * sizeof(float);
    float4* g_cb = (float4*)(ws + off); off += (size_t)NIMG * TOPK * sizeof(float4);
    int* g_lab = (int*)(ws + off); off += (size_t)NIMG * TOPK * sizeof(int);
    float4* g_ob = (float4*)(ws + off); off += (size_t)NIMG * TOPK * sizeof(float4);
    float* g_ar = (float*)(ws + off); off += (size_t)NIMG * TOPK * sizeof(float);
    int* g_nsel = (int*)(ws + off); off += 256;
    unsigned long long* g_rows = (unsigned long long*)(ws + off);
    off += (size_t)NIMG * KW * TOPK * sizeof(unsigned long long);

    k_zero<<<1, 512, 0, stream>>>(cnt);

    int gx = (NBOX + BDEC - 1) / BDEC;   // 69
    k_decode<<<dim3(gx, NIMG), BDEC, 0, stream>>>(bboxes, scores, dbox, oboxes, cand, cnt);
    k_topk<<<NIMG, 1024, 0, stream>>>(oboxes, cand, cnt, g_sc, g_cb, g_lab, g_ob, g_ar, g_nsel);
    k_iou<<<dim3(KW, NIMG), 256, 0, stream>>>(g_ob, g_ar, g_nsel, g_rows);
    k_nms<<<NIMG, 512, 0, stream>>>(g_rows, g_sc, g_cb, g_lab, g_nsel, out);
}

// Round 25
// 97.743 us; speedup vs baseline: 1.2975x; 1.2975x over previous
//
#include <hip/hip_runtime.h>
#include <cstdint>
#include <cstddef>

#define NIMG 32
#define NCLS 81
#define NC1  80
#define NBOX 8732
#define CAP  65536
#define TOPK 400
#define MAXOUT 100
#define KW   7             // 400 bits -> 7 u64 words
#define COLCAP 2048
#define BDEC 256
#define CNTSTRIDE 16       // one counter per 64B line
#define RSTRIDE 409        // LDS row stride (u64), odd -> conflict-free w-column reads

__device__ __forceinline__ unsigned int f2sort(float f) {
    unsigned int u = __float_as_uint(f);
    return (u & 0x80000000u) ? ~u : (u | 0x80000000u);
}

// ============ kernel 0: zero the per-image counters ============
__global__ __launch_bounds__(512) void k_zero(int* __restrict__ cnt) {
    cnt[threadIdx.x] = 0;    // NIMG * CNTSTRIDE = 512 ints
}

// ============ kernel 1: decode + register softmax + mul-filter + sparse emit (R17) ============
__global__ __launch_bounds__(BDEC) void k_decode(const float* __restrict__ bboxes,
        const float* __restrict__ scores, const float* __restrict__ dbox,
        float4* __restrict__ oboxes, uint2* __restrict__ cand, int* __restrict__ cnt) {
    int n = blockIdx.y;
    int b = blockIdx.x * BDEC + threadIdx.x;
    int lane = threadIdx.x & 63;
    bool live = (b < NBOX);
    int bs = live ? b : 0;

    const float* sp = scores + (size_t)n * NCLS * NBOX + bs;
    float sc[NCLS];
    #pragma unroll
    for (int c = 0; c < NCLS; ++c) sc[c] = sp[(size_t)c * NBOX];

    bool go = false;
    float l = 0.f, tt = 0.f, r = 0.f, bo = 0.f;
    if (live) {
        const float* bp = bboxes + (size_t)n * 4 * NBOX + b;
        float bx = bp[0], by = bp[NBOX], bw = bp[2 * NBOX], bh = bp[3 * NBOX];
        float4 d = reinterpret_cast<const float4*>(dbox)[b];
        float cx = 0.1f * bx * d.z + d.x;
        float cy = 0.1f * by * d.w + d.y;
        float ww = expf(0.2f * bw) * d.z;
        float hh = expf(0.2f * bh) * d.w;
        l = cx - 0.5f * ww;  tt = cy - 0.5f * hh;
        r = cx + 0.5f * ww;  bo = cy + 0.5f * hh;
        l = fminf(fmaxf(l, 0.f), 1.f);  tt = fminf(fmaxf(tt, 0.f), 1.f);
        r = fminf(fmaxf(r, 0.f), 1.f);  bo = fminf(fmaxf(bo, 0.f), 1.f);
        const float MINS = 1.0f / 300.0f;
        go = (r - l >= MINS) && (bo - tt >= MINS);
    }

    float m = -3.4e38f;
    #pragma unroll
    for (int c = 0; c < NCLS; ++c) m = fmaxf(m, sc[c]);

    float ss = 0.f;
    #pragma unroll
    for (int c = 0; c < NCLS; ++c) { sc[c] = expf(sc[c] - m); ss += sc[c]; }

    // mul-compare filter with exact gray-zone fallback (selection == (e/ss > 0.05f) exactly)
    float t05 = 0.05f * ss;
    float thi = t05 * 1.000001f;
    float tlo = t05 * 0.999999f;
    unsigned long long mlo = 0ull;   // classes 1..64
    unsigned int       mhi = 0u;     // classes 65..80
    #pragma unroll
    for (int c = 1; c < NCLS; ++c) {
        float e = sc[c];
        bool bit;
        if (e > thi)       bit = true;
        else if (e < tlo)  bit = false;
        else               bit = (e / ss > 0.05f);   // rare exact resolve
        if (go && bit) {
            if (c <= 64) mlo |= 1ull << (c - 1);
            else         mhi |= 1u << (c - 65);
        }
    }

    int nc = (int)__popcll(mlo) + __popc(mhi);
    int incl = nc;
    #pragma unroll
    for (int off = 1; off < 64; off <<= 1) {
        int u = __shfl_up(incl, off);
        if (lane >= off) incl += u;
    }
    int excl = incl - nc;
    int tot = __shfl(incl, 63);
    int base = 0;
    if (lane == 0 && tot > 0) base = atomicAdd(&cnt[n * CNTSTRIDE], tot);
    base = __shfl(base, 0);

    // sparse emit: iterate only set bits; reload candidate score (L2-hot), exact expf/div
    if (nc > 0) {
        int pos = base + excl;
        uint2* cp = cand + (size_t)n * CAP;
        unsigned long long ml = mlo;
        while (ml) {
            int bit = (int)__ffsll((long long)ml) - 1; ml &= ml - 1;
            int c = bit + 1;
            float x = sp[(size_t)c * NBOX];
            float p = expf(x - m) / ss;
            if (pos < CAP) cp[pos] = make_uint2(__float_as_uint(p),
                                                (unsigned)(b * NC1 + (c - 1)));
            ++pos;
        }
        unsigned int mh = mhi;
        while (mh) {
            int bit = __ffs(mh) - 1; mh &= mh - 1;
            int c = bit + 65;
            float x = sp[(size_t)c * NBOX];
            float p = expf(x - m) / ss;
            if (pos < CAP) cp[pos] = make_uint2(__float_as_uint(p),
                                                (unsigned)(b * NC1 + (c - 1)));
            ++pos;
        }
        oboxes[(size_t)n * NBOX + b] = make_float4(l, tt, r, bo);
    }
}

// ============ LDS bitonic sort (descending), u64 keys, n = pow2 ============
__device__ void bitonic_desc(unsigned long long* arr, int nn, int tid, int nt) {
    for (int k = 2; k <= nn; k <<= 1) {
        for (int j = k >> 1; j > 0; j >>= 1) {
            __syncthreads();
            for (int i = tid; i < nn; i += nt) {
                int ixj = i ^ j;
                if (ixj > i) {
                    unsigned long long a = arr[i], b = arr[ixj];
                    bool desc = ((i & k) == 0);
                    bool sw = desc ? (a < b) : (a > b);
                    if (sw) { arr[i] = b; arr[ixj] = a; }
                }
            }
        }
    }
    __syncthreads();
}

// ============ kernel 2: per-image top-400 selection, write records (R17 verbatim) ============
__global__ __launch_bounds__(1024) void k_topk(const float4* __restrict__ boxes,
        const uint2* __restrict__ cand, const int* __restrict__ cnt,
        float* __restrict__ g_sc, float4* __restrict__ g_cb, int* __restrict__ g_lab,
        float4* __restrict__ g_ob, float* __restrict__ g_ar, int* __restrict__ g_nsel) {
    __shared__ int hist[1024];
    __shared__ unsigned long long keys[COLCAP];
    __shared__ int s_T, s_pos;

    int n = blockIdx.x;
    int tid = threadIdx.x;
    int lane = tid & 63;
    unsigned long long lmlt = (1ull << lane) - 1ull;
    int M = cnt[n * CNTSTRIDE]; if (M > CAP) M = CAP;
    const uint2* cp = cand + (size_t)n * CAP;

    hist[tid] = 0;
    if (tid == 0) s_pos = 0;
    __syncthreads();

    for (int i = tid; i < M; i += 1024) {
        unsigned int bits = cp[i].x;
        int bk = (int)(bits >> 16) - 0x3D00;
        bk = max(0, min(1023, bk));
        atomicAdd(&hist[bk], 1);
    }
    __syncthreads();

    if (tid < 64) {
        int sl = 0;
        #pragma unroll
        for (int t = 0; t < 16; ++t) sl += hist[tid * 16 + t];
        int incl = sl;
        #pragma unroll
        for (int off = 1; off < 64; off <<= 1) {
            int v = __shfl_down(incl, off);
            if (tid + off < 64) incl += v;
        }
        int xl = incl - sl;
        int tc = -1, cum = xl;
        for (int t = 15; t >= 0; --t) {
            cum += hist[tid * 16 + t];
            if (cum >= TOPK) { tc = tid * 16 + t; break; }
        }
        #pragma unroll
        for (int off = 32; off > 0; off >>= 1)
            tc = max(tc, __shfl_xor(tc, off));
        if (tid == 0) s_T = max(tc, 0);
    }
    __syncthreads();
    int T = s_T;

    int iters = (M + 1023) / 1024;
    for (int it = 0; it < iters; ++it) {
        int i = it * 1024 + tid;
        bool pred = false; unsigned long long key = 0ull;
        if (i < M) {
            uint2 e = cp[i];
            int bk = (int)(e.x >> 16) - 0x3D00;
            bk = max(0, min(1023, bk));
            if (bk >= T) {
                pred = true;
                key = ((unsigned long long)e.x << 32) | (unsigned int)(~e.y);
            }
        }
        unsigned long long mask = __ballot(pred);
        int base = 0;
        if (lane == 0) {
            int cw = (int)__popcll(mask);
            if (cw) base = atomicAdd(&s_pos, cw);
        }
        base = __shfl(base, 0);
        if (pred) {
            int pos = base + (int)__popcll(mask & lmlt);
            if (pos < COLCAP) keys[pos] = key;
        }
    }
    __syncthreads();
    int ncol = min(s_pos, COLCAP);

    int nsort = 512;
    while (nsort < ncol) nsort <<= 1;
    for (int i = ncol + tid; i < nsort; i += 1024) keys[i] = 0ull;
    __syncthreads();
    bitonic_desc(keys, nsort, tid, 1024);

    int nsel = min(TOPK, ncol);
    if (tid < TOPK) {
        int i = tid;
        float sc = -1.0f; float4 cb = make_float4(0.f, 0.f, 0.f, 0.f);
        int lab = 0; float4 ob = cb; float ar = 0.f;
        if (i < nsel) {
            unsigned long long key = keys[i];
            unsigned int bits = (unsigned int)(key >> 32);
            unsigned int flat = ~(unsigned int)key;
            int bb = (int)(flat / NC1);
            lab = (int)(flat - (unsigned)bb * NC1) + 1;
            sc = __uint_as_float(bits);
            cb = boxes[(size_t)n * NBOX + bb];
            float off = 2.0f * (float)lab;
            ob = make_float4(cb.x + off, cb.y + off, cb.z + off, cb.w + off);
            ar = fmaxf(ob.z - ob.x, 0.f) * fmaxf(ob.w - ob.y, 0.f);
        }
        size_t gi = (size_t)n * TOPK + i;
        g_sc[gi] = sc; g_cb[gi] = cb; g_lab[gi] = lab; g_ob[gi] = ob; g_ar[gi] = ar;
    }
    if (tid == 0) g_nsel[n] = nsel;
}

// ============ kernel 3: IoU suppression-mask words, grid (KW, NIMG) ============
__global__ __launch_bounds__(256) void k_iou(const float4* __restrict__ g_ob,
        const float* __restrict__ g_ar, const int* __restrict__ g_nsel,
        unsigned long long* __restrict__ g_rows) {
    __shared__ float4 s_ob[TOPK];
    __shared__ float  s_ar[TOPK];
    int n = blockIdx.y, w = blockIdx.x;
    int tid = threadIdx.x;
    for (int i = tid; i < TOPK; i += 256) {
        s_ob[i] = g_ob[(size_t)n * TOPK + i];
        s_ar[i] = g_ar[(size_t)n * TOPK + i];
    }
    __syncthreads();
    int nsel = g_nsel[n];
    int j0 = w * 64;
    unsigned long long* gr = g_rows + ((size_t)n * KW + w) * TOPK;
    for (int i = tid; i < TOPK; i += 256) {
        unsigned long long cur = 0ull;
        if (i < nsel) {
            float4 oi = s_ob[i]; float ai = s_ar[i];
            int jend = min(j0 + 64, nsel);
            for (int j = j0; j < jend; ++j) {
                if (j > i) {
                    float4 oj = s_ob[j];
                    float lx = fmaxf(oi.x, oj.x), ly = fmaxf(oi.y, oj.y);
                    float rx = fminf(oi.z, oj.z), ry = fminf(oi.w, oj.w);
                    float inter = fmaxf(rx - lx, 0.f) * fmaxf(ry - ly, 0.f);
                    float uni = fmaxf(ai + s_ar[j] - inter, 1e-12f);
                    cur |= ((unsigned long long)(inter / uni > 0.5f)) << (j - j0);
                }
            }
        }
        gr[i] = cur;   // coalesced in i
    }
}

// ============ kernel 4: nz-skipping serial NMS + rank-compact output ============
__global__ __launch_bounds__(512) void k_nms(const unsigned long long* __restrict__ g_rows,
        const float* __restrict__ g_sc, const float4* __restrict__ g_cb,
        const int* __restrict__ g_lab, const int* __restrict__ g_nsel,
        float* __restrict__ out) {
    __shared__ unsigned long long rows[KW * RSTRIDE];   // [w][i], stride 409
    __shared__ unsigned long long nz[8];
    __shared__ unsigned long long s_keep[KW];
    __shared__ int pc[KW + 1];

    int n = blockIdx.x;
    int tid = threadIdx.x;
    int lane = tid & 63;
    int nsel = g_nsel[n];

    const unsigned long long* gr = g_rows + (size_t)n * KW * TOPK;
    for (int t = tid; t < KW * TOPK; t += 512) {
        int w = t / TOPK, i = t - w * TOPK;
        rows[w * RSTRIDE + i] = gr[t];
    }
    __syncthreads();

    {
        unsigned long long v = 0ull;
        if (tid < TOPK) {
            #pragma unroll
            for (int w = 0; w < KW; ++w) v |= rows[w * RSTRIDE + tid];
        }
        unsigned long long bal = __ballot(v != 0ull);
        if (lane == 0) nz[tid >> 6] = bal;
    }
    __syncthreads();

    if (tid < 64) {
        unsigned long long keepw = 0ull;
        if (lane < KW) {
            int lo = lane << 6;
            keepw = (nsel >= lo + 64) ? ~0ull
                  : (nsel <= lo ? 0ull : ((1ull << (nsel - lo)) - 1ull));
        }
        #pragma unroll
        for (int w = 0; w < KW; ++w) {
            unsigned long long nzw = nz[w];
            while (nzw) {
                int bq = (int)__ffsll((long long)nzw) - 1;
                nzw &= nzw - 1;
                int i = (w << 6) + bq;
                unsigned long long row = (lane < KW) ? rows[lane * RSTRIDE + i] : 0ull;
                unsigned long long kwv = __shfl(keepw, w);
                if ((kwv >> bq) & 1ull) keepw &= ~row;
            }
        }
        if (lane < KW) s_keep[lane] = keepw;
    }
    __syncthreads();

    if (tid == 0) {
        int acc = 0;
        #pragma unroll
        for (int w = 0; w < KW; ++w) { pc[w] = acc; acc += (int)__popcll(s_keep[w]); }
        pc[KW] = acc;
    }
    __syncthreads();

    float* obox = out;
    float* olab = out + (size_t)NIMG * MAXOUT * 4;
    float* osco = out + (size_t)NIMG * MAXOUT * 5;
    int nkept = pc[KW];

    if (tid < TOPK) {
        unsigned long long kw = s_keep[tid >> 6];
        bool kb = (kw >> (tid & 63)) & 1ull;
        if (kb) {
            int rank = pc[tid >> 6] + (int)__popcll(kw & ((1ull << (tid & 63)) - 1ull));
            if (rank < MAXOUT) {
                size_t gi = (size_t)n * TOPK + tid;
                float4 cb = g_cb[gi];
                size_t bo_ = ((size_t)n * MAXOUT + rank) * 4;
                obox[bo_ + 0] = cb.x; obox[bo_ + 1] = cb.y;
                obox[bo_ + 2] = cb.z; obox[bo_ + 3] = cb.w;
                olab[(size_t)n * MAXOUT + rank] = (float)g_lab[gi];
                osco[(size_t)n * MAXOUT + rank] = g_sc[gi];
            }
        }
    }
    if (tid < MAXOUT && tid >= nkept) {
        size_t bo_ = ((size_t)n * MAXOUT + tid) * 4;
        obox[bo_ + 0] = 0.f; obox[bo_ + 1] = 0.f; obox[bo_ + 2] = 0.f; obox[bo_ + 3] = 0.f;
        olab[(size_t)n * MAXOUT + tid] = 0.f;
        osco[(size_t)n * MAXOUT + tid] = 0.f;
    }
}

extern "C" void kernel_launch(void* const* d_in, const int* in_sizes, int n_in,
                              void* d_out, int out_size, void* d_ws, size_t ws_size,
                              hipStream_t stream) {
    (void)in_sizes; (void)n_in; (void)out_size; (void)ws_size;
    const float* bboxes = (const float*)d_in[0];
    const float* scores = (const float*)d_in[1];
    const float* dbox   = (const float*)d_in[2];
    float* out = (float*)d_out;

    char* ws = (char*)d_ws;
    size_t off = 0;
    float4* oboxes = (float4*)(ws + off); off += (size_t)NIMG * NBOX * sizeof(float4);
    int* cnt = (int*)(ws + off); off += (size_t)NIMG * CNTSTRIDE * sizeof(int);
    uint2* cand = (uint2*)(ws + off); off += (size_t)NIMG * CAP * sizeof(uint2);
    float* g_sc = (float*)(ws + off); off += (size_t)NIMG * TOPK * sizeof(float);
    float4* g_cb = (float4*)(ws + off); off += (size_t)NIMG * TOPK * sizeof(float4);
    int* g_lab = (int*)(ws + off); off += (size_t)NIMG * TOPK * sizeof(int);
    float4* g_ob = (float4*)(ws + off); off += (size_t)NIMG * TOPK * sizeof(float4);
    float* g_ar = (float*)(ws + off); off += (size_t)NIMG * TOPK * sizeof(float);
    int* g_nsel = (int*)(ws + off); off += 256;
    unsigned long long* g_rows = (unsigned long long*)(ws + off);
    off += (size_t)NIMG * KW * TOPK * sizeof(unsigned long long);

    k_zero<<<1, 512, 0, stream>>>(cnt);

    int gx = (NBOX + BDEC - 1) / BDEC;   // 35
    k_decode<<<dim3(gx, NIMG), BDEC, 0, stream>>>(bboxes, scores, dbox, oboxes, cand, cnt);
    k_topk<<<NIMG, 1024, 0, stream>>>(oboxes, cand, cnt, g_sc, g_cb, g_lab, g_ob, g_ar, g_nsel);
    k_iou<<<dim3(KW, NIMG), 256, 0, stream>>>(g_ob, g_ar, g_nsel, g_rows);
    k_nms<<<NIMG, 512, 0, stream>>>(g_rows, g_sc, g_cb, g_lab, g_nsel, out);
}